// Round 10
// baseline (5590.379 us; speedup 1.0000x reference)
//
#include <hip/hip_runtime.h>
#include <hip/hip_bf16.h>
#include <math.h>

#define TLEN 1022
#define SLEN 1024
#define NB   64
#define NE   256
#define NF   256
#define NH   256
#define NG   1024
#define TC   256      // chunk length (last chunk = 254)

typedef _Float16 h2_t __attribute__((ext_vector_type(2)));
typedef __attribute__((ext_vector_type(8))) short bf16x8;
typedef __attribute__((ext_vector_type(4))) float f32x4;

#if defined(__has_builtin)
# if __has_builtin(__builtin_amdgcn_fdot2)
#  define HAVE_FDOT2 1
# endif
#endif
#ifndef HAVE_FDOT2
# define HAVE_FDOT2 0
#endif

__device__ __forceinline__ float sigm(float x){ return 1.f/(1.f+__expf(-x)); }
__device__ __forceinline__ float tanh_(float x){ return 1.f - 2.f/(__expf(2.f*x)+1.f); }

__device__ __forceinline__ unsigned int packh2(float x, float y){
  h2_t p; p.x = (_Float16)x; p.y = (_Float16)y;
  return __builtin_bit_cast(unsigned int, p);
}
__device__ __forceinline__ float dot2_acc(unsigned int w, unsigned int h, float acc){
  h2_t a = __builtin_bit_cast(h2_t, w);
  h2_t b = __builtin_bit_cast(h2_t, h);
#if HAVE_FDOT2
  return __builtin_amdgcn_fdot2(a, b, acc, false);
#else
  return acc + (float)a.x*(float)b.x + (float)a.y*(float)b.y;
#endif
}
__device__ __forceinline__ unsigned short f2bf(float x){
  __hip_bfloat16 b = __float2bfloat16(x);
  return __builtin_bit_cast(unsigned short, b);
}

// bias4[g] = b_ih[g] + b_hh[g] + sum_f conv_b[f]*w_ih[g][f]
__global__ __launch_bounds__(256) void k_bias(const float* __restrict__ conv_b,
                                              const float* __restrict__ w_ih,
                                              const float* __restrict__ b_ih,
                                              const float* __restrict__ b_hh,
                                              float* __restrict__ bias4){
  int g = blockIdx.x*256 + threadIdx.x;
  const float* row = w_ih + (size_t)g*NF;
  float s = b_ih[g] + b_hh[g];
  for (int f=0; f<NF; f+=4){
    float4 w4 = *(const float4*)(row+f);
    float4 c4 = *(const float4*)(conv_b+f);
    s += w4.x*c4.x + w4.y*c4.y + w4.z*c4.z + w4.w*c4.w;
  }
  bias4[g] = s;
}

// Prepack w_hh for the SPLIT k_rnn2: per (half, cp, tid) a uint4 of f16 pairs.
// Thread tid=(wv*64+l): kq=wv>>1 (col slice 64), jh=wv&1. Element e: local row
// r2 = jh*256 + l*4 + e; global row R = (r2>>7)*256 + half*128 + (r2&127);
// cols kq*64+2cp, +1.
__global__ __launch_bounds__(256) void k_pack2(const float* __restrict__ w_hh,
                                               uint4* __restrict__ pall2){
  int gid = blockIdx.x*256 + threadIdx.x;     // 0..32767
  int half = gid >> 14, rem = gid & 16383;
  int cp = rem >> 9, tid = rem & 511;
  int l = tid & 63, wv = tid >> 6, kq = wv >> 1, jh = wv & 1;
  unsigned int c[4];
  #pragma unroll
  for (int e=0;e<4;++e){
    int r2 = jh*256 + l*4 + e;
    int R  = (r2>>7)*256 + half*128 + (r2&127);
    int col = kq*64 + 2*cp;
    const float* p = w_hh + (size_t)R*NH + col;
    c[e] = packh2(p[0], p[1]);
  }
  pall2[(size_t)(half*32 + cp)*512 + tid] = make_uint4(c[0],c[1],c[2],c[3]);
}

// CW2T[g][k] = sum_f w_ih[g][f] * conv_w_flat[k][f]   (bf16 [1024][768])
__global__ __launch_bounds__(256) void k_cw2(const float* __restrict__ w_ih,
                                             const float* __restrict__ conv_w,
                                             unsigned short* __restrict__ cw2t){
  __shared__ float al[64][17];
  __shared__ float bl[16][64];
  const int n0  = blockIdx.x*64;
  const int m0  = blockIdx.y*64;
  const int tid = threadIdx.x;
  const int ty  = tid>>4, tx = tid&15;
  const int rr  = tid>>2, kq = (tid&3)<<2;
  float acc[4][4];
  #pragma unroll
  for (int i=0;i<4;++i){ acc[i][0]=0.f; acc[i][1]=0.f; acc[i][2]=0.f; acc[i][3]=0.f; }

  for (int k0=0; k0<256; k0+=16){
    __syncthreads();
    {
      float4 v = *(const float4*)(w_ih + (size_t)(m0+rr)*NF + k0 + kq);
      al[rr][kq+0]=v.x; al[rr][kq+1]=v.y; al[rr][kq+2]=v.z; al[rr][kq+3]=v.w;
      float4 u = *(const float4*)(conv_w + (size_t)(n0+rr)*NF + k0 + kq);
      bl[kq+0][rr]=u.x; bl[kq+1][rr]=u.y; bl[kq+2][rr]=u.z; bl[kq+3][rr]=u.w;
    }
    __syncthreads();
    #pragma unroll
    for (int kk=0; kk<16; ++kk){
      float a0=al[ty*4+0][kk], a1=al[ty*4+1][kk], a2=al[ty*4+2][kk], a3=al[ty*4+3][kk];
      float4 bv = *(const float4*)&bl[kk][tx*4];
      acc[0][0]+=a0*bv.x; acc[0][1]+=a0*bv.y; acc[0][2]+=a0*bv.z; acc[0][3]+=a0*bv.w;
      acc[1][0]+=a1*bv.x; acc[1][1]+=a1*bv.y; acc[1][2]+=a1*bv.z; acc[1][3]+=a1*bv.w;
      acc[2][0]+=a2*bv.x; acc[2][1]+=a2*bv.y; acc[2][2]+=a2*bv.z; acc[2][3]+=a2*bv.w;
      acc[3][0]+=a3*bv.x; acc[3][1]+=a3*bv.y; acc[3][2]+=a3*bv.z; acc[3][3]+=a3*bv.w;
    }
  }
  #pragma unroll
  for (int i=0;i<4;++i){
    size_t r = (size_t)m0 + ty*4 + i;
    unsigned int p0 = (unsigned int)f2bf(acc[i][0]) | ((unsigned int)f2bf(acc[i][1])<<16);
    unsigned int p1 = (unsigned int)f2bf(acc[i][2]) | ((unsigned int)f2bf(acc[i][3])<<16);
    *(uint2*)(cw2t + r*768 + n0 + tx*4) = make_uint2(p0, p1);
  }
}

// Fused conv+xg GEMM (unchanged from round 7)
__global__ __launch_bounds__(256,2) void k_fxg(const int* __restrict__ ipts,
                                               const float* __restrict__ emb,
                                               const unsigned short* __restrict__ cw2t,
                                               const float* __restrict__ bias4,
                                               unsigned short* __restrict__ xh,
                                               int t0){
  __shared__ unsigned short A_l[128][72];
  __shared__ unsigned short B_l[256][72];
  __shared__ int tokl[4][64];
  const int tid = threadIdx.x;
  const int l   = tid & 63, wv = tid >> 6;
  const int m0  = blockIdx.x * 128;
  const int n0  = blockIdx.y * 256;
  const int TL0 = m0 >> 6;
  {
    int tv = tid >> 6, b = tid & 63;
    tokl[tv][b] = ipts[b*SLEN + t0 + TL0 + tv];
  }

  f32x4 acc[4][8];
  #pragma unroll
  for (int mt=0; mt<4; ++mt)
    #pragma unroll
    for (int nt=0; nt<8; ++nt)
      acc[mt][nt] = (f32x4){0.f,0.f,0.f,0.f};

  const int wm = wv >> 1, wn = wv & 1;
  const int lr = l & 15, lk = l >> 4;

  for (int ks = 0; ks < 12; ++ks){
    const int w0 = ks >> 2;
    const int e0 = (ks & 3) << 6;
    __syncthreads();
    #pragma unroll
    for (int s = 0; s < 4; ++s){
      int seg = tid + s*256;
      int row = seg >> 3, off = seg & 7;
      int tok = tokl[(row>>6) + w0][row & 63];
      const float* src = emb + (size_t)tok*NE + e0 + off*8;
      float4 f0 = *(const float4*)src;
      float4 f1 = *(const float4*)(src+4);
      unsigned int p0 = (unsigned int)f2bf(f0.x) | ((unsigned int)f2bf(f0.y)<<16);
      unsigned int p1 = (unsigned int)f2bf(f0.z) | ((unsigned int)f2bf(f0.w)<<16);
      unsigned int p2 = (unsigned int)f2bf(f1.x) | ((unsigned int)f2bf(f1.y)<<16);
      unsigned int p3 = (unsigned int)f2bf(f1.z) | ((unsigned int)f2bf(f1.w)<<16);
      *(uint4*)&A_l[row][off*8] = make_uint4(p0,p1,p2,p3);
    }
    #pragma unroll
    for (int s = 0; s < 8; ++s){
      int seg = tid + s*256;
      int row = seg >> 3, off = seg & 7;
      uint4 v = *(const uint4*)(cw2t + (size_t)(n0+row)*768 + (ks<<6) + off*8);
      *(uint4*)&B_l[row][off*8] = v;
    }
    __syncthreads();
    #pragma unroll
    for (int kf = 0; kf < 2; ++kf){
      bf16x8 af[4], bfr[8];
      #pragma unroll
      for (int mt=0; mt<4; ++mt)
        af[mt] = *(const bf16x8*)&A_l[wm*64 + mt*16 + lr][kf*32 + lk*8];
      #pragma unroll
      for (int nt=0; nt<8; ++nt)
        bfr[nt] = *(const bf16x8*)&B_l[wn*128 + nt*16 + lr][kf*32 + lk*8];
      #pragma unroll
      for (int mt=0; mt<4; ++mt)
        #pragma unroll
        for (int nt=0; nt<8; ++nt)
          acc[mt][nt] = __builtin_amdgcn_mfma_f32_16x16x32_bf16(af[mt], bfr[nt], acc[mt][nt], 0,0,0);
    }
  }

  float bia[8];
  #pragma unroll
  for (int nt=0; nt<8; ++nt) bia[nt] = bias4[n0 + wn*128 + nt*16 + lr];
  #pragma unroll
  for (int mt=0; mt<4; ++mt){
    #pragma unroll
    for (int nt=0; nt<8; ++nt){
      #pragma unroll
      for (int r=0; r<4; ++r){
        int row = m0 + wm*64 + mt*16 + lk*4 + r;
        int col = n0 + wn*128 + nt*16 + lr;
        _Float16 hv = (_Float16)(acc[mt][nt][r] + bia[nt]);
        xh[(size_t)row*NG + col] = __builtin_bit_cast(unsigned short, hv);
      }
    }
  }
}

// LSTM chunk, HIDDEN-SPLIT: 128 WGs = (b = wg&63, half = wg>>6) x 512 threads.
// WG owns hidden units [half*128, half*128+128) -> 512 gate rows, 256 KB weights
// = 128 KB LDS (cp<16) + 64 VGPR/thread (cp>=16). Per-step h-half exchange via
// step-indexed global slots + device-scope flags (flags memset to 0 per launch).
__global__ __attribute__((amdgpu_flat_work_group_size(512,512)))
__attribute__((amdgpu_waves_per_eu(2,2)))
void k_rnn2(const unsigned short* __restrict__ xh,
            const uint4* __restrict__ pall2,
            const float* __restrict__ h0,
            const float* __restrict__ c0,
            const int* __restrict__ seqlen,
            unsigned int* __restrict__ h_ws,
            float* __restrict__ c_ws,
            float* __restrict__ ms_ws,
            unsigned short* __restrict__ hxu,
            unsigned int* __restrict__ flags,
            int t0, int tcount, int is_first){
  __shared__ uint4 wlds4[16][512];     // 128 KB weight pairs, cp in [0,16)
  __shared__ float part[4][520];       // per-kq partials, padded
  __shared__ unsigned int hp[128];     // FULL h (256) as f16 pairs
  const int tid  = threadIdx.x;
  const int b    = blockIdx.x & 63;
  const int half = blockIdx.x >> 6;    // pair (b, b+64): same XCD under mod-8 rr
  const int l = tid & 63, wv = tid >> 6;
  const int kq = wv >> 1, jh = wv & 1;

  const uint4* pw = pall2 + (size_t)(half*32)*512;
  #pragma unroll
  for (int cp=0; cp<16; ++cp)
    wlds4[cp][tid] = pw[(size_t)cp*512 + tid];

  unsigned int wreg[64];
  #pragma unroll
  for (int cp=16; cp<32; ++cp){
    uint4 v = pw[(size_t)cp*512 + tid];
    wreg[(cp-16)*4+0]=v.x; wreg[(cp-16)*4+1]=v.y;
    wreg[(cp-16)*4+2]=v.z; wreg[(cp-16)*4+3]=v.w;
  }
  #pragma unroll
  for (int i=0;i<64;++i) asm volatile("" : "+v"(wreg[i]));

  float creg = 0.f, msum = 0.f;
  if (is_first){
    if (tid < 128){
      hp[tid] = packh2(h0[(size_t)b*NH + 2*tid], h0[(size_t)b*NH + 2*tid + 1]);
      creg = c0[(size_t)b*NH + half*128 + tid];
    }
  } else {
    if (tid < 128){
      hp[tid] = h_ws[b*128 + tid];
      creg = c_ws[b*256 + half*128 + tid];
      msum = ms_ws[b*256 + half*128 + tid];
    }
  }
  const int L = seqlen[b];
  const int slot_own  = (b*2 + half)*256;
  const int slot_part = (b*2 + (1-half))*256;
  __syncthreads();

  for (int tl=0; tl<tcount; ++tl){
    // prefetch this step's xg (raw f16 bits; used after barrier)
    unsigned short xr0=0, xr1=0, xr2=0, xr3=0;
    if (tid < 128){
      const unsigned short* xp = xh + ((size_t)tl*NB + b)*NG + half*128 + tid;
      xr0 = xp[0]; xr1 = xp[256]; xr2 = xp[512]; xr3 = xp[768];
    }

    float pa[4] = {0.f,0.f,0.f,0.f};
    #pragma unroll
    for (int c=0; c<8; ++c){
      uint4 hv = *(const uint4*)&hp[kq*32 + 4*c];
      unsigned int hvv[4] = {hv.x, hv.y, hv.z, hv.w};
      #pragma unroll
      for (int e=0; e<4; ++e){
        const int cp = 4*c + e;
        uint4 wv4;
        if (cp < 16) wv4 = wlds4[cp][tid];
        else         wv4 = make_uint4(wreg[(cp-16)*4+0], wreg[(cp-16)*4+1],
                                      wreg[(cp-16)*4+2], wreg[(cp-16)*4+3]);
        pa[0] = dot2_acc(wv4.x, hvv[e], pa[0]);
        pa[1] = dot2_acc(wv4.y, hvv[e], pa[1]);
        pa[2] = dot2_acc(wv4.z, hvv[e], pa[2]);
        pa[3] = dot2_acc(wv4.w, hvv[e], pa[3]);
      }
    }
    *(float4*)&part[kq][jh*256 + l*4] = make_float4(pa[0],pa[1],pa[2],pa[3]);
    __syncthreads();                                   // (1) partials ready

    if (tid < 128){
      unsigned short xr4[4] = {xr0, xr1, xr2, xr3};
      float a[4];
      #pragma unroll
      for (int g=0; g<4; ++g){
        float s = (float)__builtin_bit_cast(_Float16, xr4[g]);
        #pragma unroll
        for (int k=0;k<4;++k) s += part[k][g*128 + tid];
        a[g] = s;
      }
      float si = sigm(a[0]), sf = sigm(a[1]), so = sigm(a[3]);
      float tg = tanh_(a[2]);
      creg = sf*creg + si*tg;
      float h2 = so*tanh_(creg);
      if (t0 + tl < L) msum += h2;
      _Float16 hf = (_Float16)h2;
      ((_Float16*)hp)[half*128 + tid] = hf;            // own half -> LDS
      hxu[(size_t)(slot_own + tl)*128 + tid] = __builtin_bit_cast(unsigned short, hf);
    }
    __syncthreads();                                   // (2) payload written

    if (tid == 0){
      __threadfence();                                 // agent-scope writeback
      __hip_atomic_store(&flags[slot_own + tl], (unsigned int)(t0 + tl + 1),
                         __ATOMIC_RELEASE, __HIP_MEMORY_SCOPE_AGENT);
      const unsigned int want = (unsigned int)(t0 + tl + 1);
      while (__hip_atomic_load(&flags[slot_part + tl],
                               __ATOMIC_ACQUIRE, __HIP_MEMORY_SCOPE_AGENT) != want){
        __builtin_amdgcn_s_sleep(1);
      }
    }
    __syncthreads();                                   // (3) partner ready
    if (tid < 64){
      const unsigned int* src = (const unsigned int*)(hxu + (size_t)(slot_part + tl)*128);
      unsigned int v = __hip_atomic_load(src + tid, __ATOMIC_RELAXED, __HIP_MEMORY_SCOPE_AGENT);
      hp[(1-half)*64 + tid] = v;                       // partner half -> LDS
    }
    __syncthreads();                                   // (4) hp complete
  }

  if (half == 0 && tid < 128) h_ws[b*128 + tid] = hp[tid];
  if (tid < 128){
    c_ws[b*256 + half*128 + tid]  = creg;
    ms_ws[b*256 + half*128 + tid] = msum;
  }
}

// final: out[b] = sigmoid( (1/L) * sum_j ms[b][j]*lin_w[j] + lin_b )
__global__ __launch_bounds__(64) void k_fin(const float* __restrict__ ms_ws,
                                            const int* __restrict__ seqlen,
                                            const float* __restrict__ lin_w,
                                            const float* __restrict__ lin_b,
                                            float* __restrict__ out){
  int b = threadIdx.x;
  const float* m = ms_ws + (size_t)b*256;
  float s = 0.f;
  for (int j=0;j<256;j+=4){
    float4 mv = *(const float4*)(m+j);
    float4 wv = *(const float4*)(lin_w+j);
    s += mv.x*wv.x + mv.y*wv.y + mv.z*wv.z + mv.w*wv.w;
  }
  out[b] = sigm(s / (float)seqlen[b] + lin_b[0]);
}

extern "C" void kernel_launch(void* const* d_in, const int* in_sizes, int n_in,
                              void* d_out, int out_size, void* d_ws, size_t ws_size,
                              hipStream_t stream){
  const int*   ipts   = (const int*)d_in[0];
  const int*   seqlen = (const int*)d_in[1];
  const float* h0     = (const float*)d_in[2];
  const float* c0     = (const float*)d_in[3];
  const float* emb    = (const float*)d_in[4];
  const float* conv_w = (const float*)d_in[5];
  const float* conv_b = (const float*)d_in[6];
  const float* w_ih   = (const float*)d_in[7];
  const float* w_hh   = (const float*)d_in[8];
  const float* b_ih   = (const float*)d_in[9];
  const float* b_hh   = (const float*)d_in[10];
  const float* lin_w  = (const float*)d_in[11];
  const float* lin_b  = (const float*)d_in[12];
  float* out = (float*)d_out;

  char* ws = (char*)d_ws;
  const size_t XH_B   = (size_t)TC*NB*NG*2;       // 33.55 MB
  const size_t CW2_B  = (size_t)NG*768*2;         // 1.57 MB
  const size_t PALL_B = (size_t)64*512*16;        // 512 KB
  const size_t FLAG_B = (size_t)NB*2*TC*4;        // 128 KB
  size_t off = 0;
  unsigned short* xh    = (unsigned short*)(ws + off); off += XH_B;
  unsigned short* cw2t  = (unsigned short*)(ws + off); off += CW2_B;
  uint4*          pall2 = (uint4*)(ws + off);          off += PALL_B;
  float*          bias4 = (float*)(ws + off);          off += 4096;
  unsigned int*   h_ws  = (unsigned int*)(ws + off);   off += 32768;
  float*          c_ws  = (float*)(ws + off);          off += 65536;
  float*          ms_ws = (float*)(ws + off);          off += 65536;
  unsigned int*   flags = (unsigned int*)(ws + off);   off += FLAG_B;
  unsigned short* hxu   = (unsigned short*)(ws + off); // 8 MB

  hipMemsetAsync(flags, 0, FLAG_B, stream);

  k_bias <<<dim3(4),      dim3(256), 0, stream>>>(conv_b, w_ih, b_ih, b_hh, bias4);
  k_pack2<<<dim3(128),    dim3(256), 0, stream>>>(w_hh, pall2);
  k_cw2  <<<dim3(12, 16), dim3(256), 0, stream>>>(w_ih, conv_w, cw2t);

  for (int t0 = 0; t0 < TLEN; t0 += TC){
    int tcount = (TLEN - t0 < TC) ? (TLEN - t0) : TC;
    int is_first = (t0 == 0);
    k_fxg <<<dim3(128, 4), dim3(256), 0, stream>>>(ipts, emb, cw2t, bias4, xh, t0);
    k_rnn2<<<dim3(128),    dim3(512), 0, stream>>>(xh, pall2, h0, c0, seqlen,
                                                   h_ws, c_ws, ms_ws, hxu, flags,
                                                   t0, tcount, is_first);
  }
  k_fin<<<dim3(1), dim3(64), 0, stream>>>(ms_ws, seqlen, lin_w, lin_b, out);
}

// Round 11
// 1372.039 us; speedup vs baseline: 4.0745x; 4.0745x over previous
//
#include <hip/hip_runtime.h>
#include <hip/hip_bf16.h>
#include <math.h>

#define TLEN 1022
#define SLEN 1024
#define NB   64
#define NE   256
#define NF   256
#define NH   256
#define NG   1024
#define TC   256      // chunk length (last chunk = 254)
#define CQL  6        // col-quads (of 16) whose weights live in LDS; rest in VGPRs

typedef _Float16 h2_t __attribute__((ext_vector_type(2)));
typedef __attribute__((ext_vector_type(8))) short bf16x8;
typedef __attribute__((ext_vector_type(4))) float f32x4;

#if defined(__has_builtin)
# if __has_builtin(__builtin_amdgcn_sdot4)
#  define HAVE_SDOT4 1
# endif
#endif
#ifndef HAVE_SDOT4
# define HAVE_SDOT4 0
#endif

__device__ __forceinline__ float sigm(float x){ return 1.f/(1.f+__expf(-x)); }
__device__ __forceinline__ float tanh_(float x){ return 1.f - 2.f/(__expf(2.f*x)+1.f); }

__device__ __forceinline__ int sdot4_acc(unsigned int a, unsigned int b, int acc){
#if HAVE_SDOT4
  return __builtin_amdgcn_sdot4((int)a, (int)b, acc, false);
#else
  int s = acc;
  #pragma unroll
  for (int e=0;e<4;++e){
    int av = (int)(signed char)((a >> (8*e)) & 0xff);
    int bv = (int)(signed char)((b >> (8*e)) & 0xff);
    s += av*bv;
  }
  return s;
#endif
}
__device__ __forceinline__ unsigned short f2bf(float x){
  __hip_bfloat16 b = __float2bfloat16(x);
  return __builtin_bit_cast(unsigned short, b);
}

// bias4[g] = b_ih[g] + b_hh[g] + sum_f conv_b[f]*w_ih[g][f]
__global__ __launch_bounds__(256) void k_bias(const float* __restrict__ conv_b,
                                              const float* __restrict__ w_ih,
                                              const float* __restrict__ b_ih,
                                              const float* __restrict__ b_hh,
                                              float* __restrict__ bias4){
  int g = blockIdx.x*256 + threadIdx.x;
  const float* row = w_ih + (size_t)g*NF;
  float s = b_ih[g] + b_hh[g];
  for (int f=0; f<NF; f+=4){
    float4 w4 = *(const float4*)(row+f);
    float4 c4 = *(const float4*)(conv_b+f);
    s += w4.x*c4.x + w4.y*c4.y + w4.z*c4.z + w4.w*c4.w;
  }
  bias4[g] = s;
}

// per-row quantization scales for w_hh: stepv[row] = rowmax/127, sws[row]=stepv/127
__global__ __launch_bounds__(256) void k_scale(const float* __restrict__ w_hh,
                                               float* __restrict__ stepv,
                                               float* __restrict__ sws){
  int row = blockIdx.x*256 + threadIdx.x;
  const float* p = w_hh + (size_t)row*NH;
  float m = 0.f;
  for (int c=0;c<NH;c+=4){
    float4 v = *(const float4*)(p+c);
    m = fmaxf(m, fmaxf(fmaxf(fabsf(v.x),fabsf(v.y)), fmaxf(fabsf(v.z),fabsf(v.w))));
  }
  float st = fmaxf(m, 1e-20f) / 127.f;
  stepv[row] = st;
  sws[row]   = st / 127.f;
}

// Pack w_hh -> i8, per-thread layout for k_rnn3.
// Word (cq, rp, tid5): tid5=(wv*64+l), kq=wv>>1, jh=wv&1; r=rp*2+w2;
// row = jh*512 + l*8 + r; byte e = col kq*64 + cq*4 + e, value rn(w/stepv[row]).
__global__ __launch_bounds__(256) void k_pack3(const float* __restrict__ w_hh,
                                               const float* __restrict__ stepv,
                                               uint2* __restrict__ pq2){
  int gid = blockIdx.x*256 + threadIdx.x;   // 0..32767
  int tid5 = gid & 511, rp = (gid>>9)&3, cq = gid>>11;
  int l = tid5 & 63, wv = tid5 >> 6, kq = wv >> 1, jh = wv & 1;
  unsigned int words[2];
  #pragma unroll
  for (int w2=0; w2<2; ++w2){
    int r = rp*2 + w2;
    int row = jh*512 + l*8 + r;
    float st = stepv[row];
    unsigned int acc = 0;
    #pragma unroll
    for (int e=0;e<4;++e){
      int col = kq*64 + cq*4 + e;
      int q = __float2int_rn(w_hh[(size_t)row*NH + col] / st);
      q = max(-127, min(127, q));
      acc |= ((unsigned int)(unsigned char)(signed char)q) << (8*e);
    }
    words[w2] = acc;
  }
  pq2[(size_t)(cq*4 + rp)*512 + tid5] = make_uint2(words[0], words[1]);
}

// CW2T[g][k] = sum_f w_ih[g][f] * conv_w_flat[k][f]   (bf16 [1024][768])
__global__ __launch_bounds__(256) void k_cw2(const float* __restrict__ w_ih,
                                             const float* __restrict__ conv_w,
                                             unsigned short* __restrict__ cw2t){
  __shared__ float al[64][17];
  __shared__ float bl[16][64];
  const int n0  = blockIdx.x*64;
  const int m0  = blockIdx.y*64;
  const int tid = threadIdx.x;
  const int ty  = tid>>4, tx = tid&15;
  const int rr  = tid>>2, kq = (tid&3)<<2;
  float acc[4][4];
  #pragma unroll
  for (int i=0;i<4;++i){ acc[i][0]=0.f; acc[i][1]=0.f; acc[i][2]=0.f; acc[i][3]=0.f; }

  for (int k0=0; k0<256; k0+=16){
    __syncthreads();
    {
      float4 v = *(const float4*)(w_ih + (size_t)(m0+rr)*NF + k0 + kq);
      al[rr][kq+0]=v.x; al[rr][kq+1]=v.y; al[rr][kq+2]=v.z; al[rr][kq+3]=v.w;
      float4 u = *(const float4*)(conv_w + (size_t)(n0+rr)*NF + k0 + kq);
      bl[kq+0][rr]=u.x; bl[kq+1][rr]=u.y; bl[kq+2][rr]=u.z; bl[kq+3][rr]=u.w;
    }
    __syncthreads();
    #pragma unroll
    for (int kk=0; kk<16; ++kk){
      float a0=al[ty*4+0][kk], a1=al[ty*4+1][kk], a2=al[ty*4+2][kk], a3=al[ty*4+3][kk];
      float4 bv = *(const float4*)&bl[kk][tx*4];
      acc[0][0]+=a0*bv.x; acc[0][1]+=a0*bv.y; acc[0][2]+=a0*bv.z; acc[0][3]+=a0*bv.w;
      acc[1][0]+=a1*bv.x; acc[1][1]+=a1*bv.y; acc[1][2]+=a1*bv.z; acc[1][3]+=a1*bv.w;
      acc[2][0]+=a2*bv.x; acc[2][1]+=a2*bv.y; acc[2][2]+=a2*bv.z; acc[2][3]+=a2*bv.w;
      acc[3][0]+=a3*bv.x; acc[3][1]+=a3*bv.y; acc[3][2]+=a3*bv.z; acc[3][3]+=a3*bv.w;
    }
  }
  #pragma unroll
  for (int i=0;i<4;++i){
    size_t r = (size_t)m0 + ty*4 + i;
    unsigned int p0 = (unsigned int)f2bf(acc[i][0]) | ((unsigned int)f2bf(acc[i][1])<<16);
    unsigned int p1 = (unsigned int)f2bf(acc[i][2]) | ((unsigned int)f2bf(acc[i][3])<<16);
    *(uint2*)(cw2t + r*768 + n0 + tx*4) = make_uint2(p0, p1);
  }
}

// Fused conv+xg GEMM (unchanged from round 7)
__global__ __launch_bounds__(256,2) void k_fxg(const int* __restrict__ ipts,
                                               const float* __restrict__ emb,
                                               const unsigned short* __restrict__ cw2t,
                                               const float* __restrict__ bias4,
                                               unsigned short* __restrict__ xh,
                                               int t0){
  __shared__ unsigned short A_l[128][72];
  __shared__ unsigned short B_l[256][72];
  __shared__ int tokl[4][64];
  const int tid = threadIdx.x;
  const int l   = tid & 63, wv = tid >> 6;
  const int m0  = blockIdx.x * 128;
  const int n0  = blockIdx.y * 256;
  const int TL0 = m0 >> 6;
  {
    int tv = tid >> 6, b = tid & 63;
    tokl[tv][b] = ipts[b*SLEN + t0 + TL0 + tv];
  }

  f32x4 acc[4][8];
  #pragma unroll
  for (int mt=0; mt<4; ++mt)
    #pragma unroll
    for (int nt=0; nt<8; ++nt)
      acc[mt][nt] = (f32x4){0.f,0.f,0.f,0.f};

  const int wm = wv >> 1, wn = wv & 1;
  const int lr = l & 15, lk = l >> 4;

  for (int ks = 0; ks < 12; ++ks){
    const int w0 = ks >> 2;
    const int e0 = (ks & 3) << 6;
    __syncthreads();
    #pragma unroll
    for (int s = 0; s < 4; ++s){
      int seg = tid + s*256;
      int row = seg >> 3, off = seg & 7;
      int tok = tokl[(row>>6) + w0][row & 63];
      const float* src = emb + (size_t)tok*NE + e0 + off*8;
      float4 f0 = *(const float4*)src;
      float4 f1 = *(const float4*)(src+4);
      unsigned int p0 = (unsigned int)f2bf(f0.x) | ((unsigned int)f2bf(f0.y)<<16);
      unsigned int p1 = (unsigned int)f2bf(f0.z) | ((unsigned int)f2bf(f0.w)<<16);
      unsigned int p2 = (unsigned int)f2bf(f1.x) | ((unsigned int)f2bf(f1.y)<<16);
      unsigned int p3 = (unsigned int)f2bf(f1.z) | ((unsigned int)f2bf(f1.w)<<16);
      *(uint4*)&A_l[row][off*8] = make_uint4(p0,p1,p2,p3);
    }
    #pragma unroll
    for (int s = 0; s < 8; ++s){
      int seg = tid + s*256;
      int row = seg >> 3, off = seg & 7;
      uint4 v = *(const uint4*)(cw2t + (size_t)(n0+row)*768 + (ks<<6) + off*8);
      *(uint4*)&B_l[row][off*8] = v;
    }
    __syncthreads();
    #pragma unroll
    for (int kf = 0; kf < 2; ++kf){
      bf16x8 af[4], bfr[8];
      #pragma unroll
      for (int mt=0; mt<4; ++mt)
        af[mt] = *(const bf16x8*)&A_l[wm*64 + mt*16 + lr][kf*32 + lk*8];
      #pragma unroll
      for (int nt=0; nt<8; ++nt)
        bfr[nt] = *(const bf16x8*)&B_l[wn*128 + nt*16 + lr][kf*32 + lk*8];
      #pragma unroll
      for (int mt=0; mt<4; ++mt)
        #pragma unroll
        for (int nt=0; nt<8; ++nt)
          acc[mt][nt] = __builtin_amdgcn_mfma_f32_16x16x32_bf16(af[mt], bfr[nt], acc[mt][nt], 0,0,0);
    }
  }

  float bia[8];
  #pragma unroll
  for (int nt=0; nt<8; ++nt) bia[nt] = bias4[n0 + wn*128 + nt*16 + lr];
  #pragma unroll
  for (int mt=0; mt<4; ++mt){
    #pragma unroll
    for (int nt=0; nt<8; ++nt){
      #pragma unroll
      for (int r=0; r<4; ++r){
        int row = m0 + wm*64 + mt*16 + lk*4 + r;
        int col = n0 + wn*128 + nt*16 + lr;
        _Float16 hv = (_Float16)(acc[mt][nt][r] + bia[nt]);
        xh[(size_t)row*NG + col] = __builtin_bit_cast(unsigned short, hv);
      }
    }
  }
}

// LSTM chunk, i8 recurrent weights. 64 WGs x 512 threads (8 waves, 2/SIMD).
// Thread (kq=wv>>1, jh=wv&1, l): rows jh*512+l*8+r (r<8), cols kq*64..+64.
// Weights (i8): cq in [0,CQL) -> LDS wlds (96 KB); cq in [CQL,16) -> 80 VGPRs.
// Total on-CU = 256 KB, declared reg demand ~117 < the 128-reg grant
// (round-10 precedent: demand<grant is honored). MAC: v_dot4_i32_i8.
__global__ __attribute__((amdgpu_flat_work_group_size(512,512)))
__attribute__((amdgpu_waves_per_eu(2,2)))
void k_rnn3(const unsigned short* __restrict__ xh,
            const uint2* __restrict__ pq2,
            const float* __restrict__ sws,
            const float* __restrict__ h0,
            const float* __restrict__ c0,
            const int* __restrict__ seqlen,
            const float* __restrict__ lin_w,
            const float* __restrict__ lin_b,
            float* __restrict__ h_ws,
            float* __restrict__ c_ws,
            float* __restrict__ ms_ws,
            float* __restrict__ out,
            int t0, int tcount, int is_first, int is_last){
  __shared__ uint2 wlds[CQL*4][512];        // 96 KB i8 weights (cq<CQL)
  __shared__ float part2[4][2][8][68];      // 17 KB
  __shared__ unsigned int hq32[64];         // h quantized i8, packed
  __shared__ float red[256];
  const int b   = blockIdx.x;
  const int tid = threadIdx.x;
  const int l   = tid & 63, wv = tid >> 6;
  const int kq  = wv >> 1, jh = wv & 1;
  const int jbase = jh*512 + l*8;

  // stage LDS weights
  #pragma unroll
  for (int i=0;i<CQL*4;++i) wlds[i][tid] = pq2[(size_t)i*512 + tid];

  // register weights: cq in [CQL,16)
  unsigned int wreg[(16-CQL)*8];
  #pragma unroll
  for (int cq=CQL; cq<16; ++cq){
    #pragma unroll
    for (int rp=0; rp<4; ++rp){
      uint2 v = pq2[(size_t)(cq*4+rp)*512 + tid];
      wreg[(cq-CQL)*8 + rp*2 + 0] = v.x;
      wreg[(cq-CQL)*8 + rp*2 + 1] = v.y;
    }
  }
  #pragma unroll
  for (int i=0;i<(16-CQL)*8;++i) asm volatile("" : "+v"(wreg[i]));

  // per-row scales (w_step/127, folds h scale)
  float swr[8];
  #pragma unroll
  for (int r=0;r<8;++r) swr[r] = sws[jbase + r];

  float creg = 0.f, msum = 0.f, hlast = 0.f;
  if (tid < 256){
    float hv;
    if (is_first){ hv = h0[(size_t)b*NH + tid]; creg = c0[(size_t)b*NH + tid]; }
    else { hv = h_ws[b*256 + tid]; creg = c_ws[b*256 + tid]; msum = ms_ws[b*256 + tid]; }
    hlast = hv;
    int q = __float2int_rn(hv * 127.f);
    q = max(-127, min(127, q));
    ((signed char*)hq32)[tid] = (signed char)q;
  }
  const int L = seqlen[b];
  __syncthreads();

  const unsigned short* xrow = xh + (size_t)b*NG + tid;

  for (int tl=0; tl<tcount; ++tl){
    // prefetch xg (raw f16 bits; consumed after barrier)
    unsigned short xr0=0, xr1=0, xr2=0, xr3=0;
    if (tid < 256){
      const unsigned short* xr = xrow + (size_t)tl*NB*NG;
      xr0 = xr[0]; xr1 = xr[256]; xr2 = xr[512]; xr3 = xr[768];
    }

    int pa[8];
    #pragma unroll
    for (int r=0;r<8;++r) pa[r]=0;

    #pragma unroll
    for (int cq=0; cq<16; ++cq){
      unsigned int hw = hq32[kq*16 + cq];
      if (cq < CQL){
        #pragma unroll
        for (int rp=0; rp<4; ++rp){
          uint2 wv2 = wlds[cq*4+rp][tid];
          pa[rp*2+0] = sdot4_acc(wv2.x, hw, pa[rp*2+0]);
          pa[rp*2+1] = sdot4_acc(wv2.y, hw, pa[rp*2+1]);
        }
      } else {
        #pragma unroll
        for (int r=0;r<8;++r)
          pa[r] = sdot4_acc(wreg[(cq-CQL)*8 + r], hw, pa[r]);
      }
    }

    #pragma unroll
    for (int r=0;r<8;++r) part2[kq][jh][r][l] = (float)pa[r] * swr[r];
    __syncthreads();

    if (tid < 256){
      unsigned short xr4[4] = {xr0, xr1, xr2, xr3};
      float a[4];
      #pragma unroll
      for (int q=0;q<4;++q){
        int G = q*256 + tid;
        int jh2 = G>>9, rw = G&511, l2 = rw>>3, r2 = rw&7;
        float s = (float)__builtin_bit_cast(_Float16, xr4[q]);
        #pragma unroll
        for (int k=0;k<4;++k) s += part2[k][jh2][r2][l2];
        a[q] = s;
      }
      float si = sigm(a[0]), sf = sigm(a[1]), so = sigm(a[3]);
      float tg = tanh_(a[2]);
      creg = sf*creg + si*tg;
      float h2 = so*tanh_(creg);
      if (t0 + tl < L) msum += h2;
      hlast = h2;
      int q2 = __float2int_rn(h2 * 127.f);
      q2 = max(-127, min(127, q2));
      ((signed char*)hq32)[tid] = (signed char)q2;
    }
    __syncthreads();
  }

  if (tid < 256){
    h_ws[b*256 + tid]  = hlast;
    c_ws[b*256 + tid]  = creg;
    ms_ws[b*256 + tid] = msum;
  }

  if (is_last){
    if (tid < 256) red[tid] = (msum / (float)L) * lin_w[tid];
    __syncthreads();
    if (tid < 64){
      float s = red[tid] + red[tid+64] + red[tid+128] + red[tid+192];
      #pragma unroll
      for (int off=32; off>0; off>>=1) s += __shfl_down(s, off);
      if (tid==0) out[b] = sigm(s + lin_b[0]);
    }
  }
}

extern "C" void kernel_launch(void* const* d_in, const int* in_sizes, int n_in,
                              void* d_out, int out_size, void* d_ws, size_t ws_size,
                              hipStream_t stream){
  const int*   ipts   = (const int*)d_in[0];
  const int*   seqlen = (const int*)d_in[1];
  const float* h0     = (const float*)d_in[2];
  const float* c0     = (const float*)d_in[3];
  const float* emb    = (const float*)d_in[4];
  const float* conv_w = (const float*)d_in[5];
  const float* conv_b = (const float*)d_in[6];
  const float* w_ih   = (const float*)d_in[7];
  const float* w_hh   = (const float*)d_in[8];
  const float* b_ih   = (const float*)d_in[9];
  const float* b_hh   = (const float*)d_in[10];
  const float* lin_w  = (const float*)d_in[11];
  const float* lin_b  = (const float*)d_in[12];
  float* out = (float*)d_out;

  char* ws = (char*)d_ws;
  const size_t XH_B   = (size_t)TC*NB*NG*2;       // 33.55 MB
  const size_t CW2_B  = (size_t)NG*768*2;         // 1.57 MB
  const size_t PQ_B   = (size_t)16*4*512*8;       // 256 KB
  size_t off = 0;
  unsigned short* xh    = (unsigned short*)(ws + off); off += XH_B;
  unsigned short* cw2t  = (unsigned short*)(ws + off); off += CW2_B;
  uint2*          pq2   = (uint2*)(ws + off);          off += PQ_B;
  float*          stepv = (float*)(ws + off);          off += 4096;
  float*          sws   = (float*)(ws + off);          off += 4096;
  float*          bias4 = (float*)(ws + off);          off += 4096;
  float*          h_ws  = (float*)(ws + off);          off += 65536;
  float*          c_ws  = (float*)(ws + off);          off += 65536;
  float*          ms_ws = (float*)(ws + off);          off += 65536;

  k_bias <<<dim3(4),      dim3(256), 0, stream>>>(conv_b, w_ih, b_ih, b_hh, bias4);
  k_scale<<<dim3(4),      dim3(256), 0, stream>>>(w_hh, stepv, sws);
  k_pack3<<<dim3(128),    dim3(256), 0, stream>>>(w_hh, stepv, pq2);
  k_cw2  <<<dim3(12, 16), dim3(256), 0, stream>>>(w_ih, conv_w, cw2t);

  for (int t0 = 0; t0 < TLEN; t0 += TC){
    int tcount = (TLEN - t0 < TC) ? (TLEN - t0) : TC;
    int is_first = (t0 == 0), is_last = (t0 + TC >= TLEN);
    k_fxg <<<dim3(128, 4), dim3(256), 0, stream>>>(ipts, emb, cw2t, bias4, xh, t0);
    k_rnn3<<<dim3(NB),     dim3(512), 0, stream>>>(xh, pq2, sws, h0, c0, seqlen,
                                                   lin_w, lin_b, h_ws, c_ws, ms_ws, out,
                                                   t0, tcount, is_first, is_last);
  }
}